// Round 1
// baseline (404.954 us; speedup 1.0000x reference)
//
#include <hip/hip_runtime.h>
#include <hip/hip_bf16.h>

// CausalAttention: q=xWq,k=xWk,v=xWv; S=qk^T; causal mask (j>i -> -inf);
// softmax over AXIS=1 (query axis, COLUMN-wise over i) of S/32; out = W @ v.
// Strategy: P[i,j]=exp(s_ij/32), l_j=sum_{i>=j} P (fused in P-GEMM epilogue),
// fold 1/l_j into V rows -> out = P @ (V/l)^T.
// R6: all three GEMMs moved from the 128^2 / 2-barrier structure (~1000 TF,
// MfmaUtil 44%) to the 256^2 8-phase counted-vmcnt template (T3+T4+T5):
//   256x256 tile, BK=64, 8 waves (2Mx4N), 512 thr, 128KB LDS (2 dbuf x 2 half
//   x {A,B}), 1 block/CU. Per phase: 12 ds_read_b128 -> 1 half-tile stage
//   (2x global_load_lds x16B) -> s_barrier -> setprio(1) -> 16 MFMA ->
//   setprio(0) -> [vmcnt(4) @ phases 4,8 only] -> s_barrier. Loads stay in
//   flight across barriers (never vmcnt(0) in-loop).
// Stage schedule per iter (tiles t even=buf0 ph1-4, t+1=buf1 ph5-8), consume
// order (A0B0),(A0B1),(A1B0),(A1B1):
//   ph1:A1(t+1) ph2:B1(t+1) ph3:A0(t+2) ph4:B0(t+2)+vmcnt4
//   ph5:A1(t+2) ph6:B1(t+2) ph7:A0(t+3) ph8:B0(t+3)+vmcnt4
// Every slot is staged exactly one phase after its last consumer's lgkmcnt
// (safe via the double barrier), and every half lands >=1 boundary-vmcnt
// before first use. Out-of-range K-tiles are SOURCE-CLAMPED, never skipped,
// so per-wave vmcnt counts stay uniform.
// LDS XOR swizzle kept from R3 (0 bank conflicts): phys 16B chunk =
// logical ^ (row&7); global source pre-swizzled so global_load_lds dest
// stays linear. XCD swizzle + banded traversal kept (R4/R5).
// __launch_bounds__(512,2): caps VGPR at 256 (acc 128 + frags 48 + addr).

using bf16 = __hip_bfloat16;
typedef __attribute__((ext_vector_type(8))) short short8;
typedef __attribute__((ext_vector_type(4))) float f32x4;
typedef unsigned long long ull;

__device__ __forceinline__ float bfbits2f(unsigned short u) {
  return __uint_as_float((unsigned)u << 16);
}

// ---------------- fp32 -> bf16 convert (x4 per thread) ----------------
__global__ void cvt_kernel(const float* __restrict__ in, bf16* __restrict__ out) {
  size_t i = ((size_t)blockIdx.x * 256 + threadIdx.x) * 4;
  float4 v = *(const float4*)(in + i);
  alignas(8) bf16 h[4] = {__float2bfloat16(v.x), __float2bfloat16(v.y),
                          __float2bfloat16(v.z), __float2bfloat16(v.w)};
  *(unsigned long long*)(out + i) = *(const unsigned long long*)h;
}

// ------- W[k][n] fp32 -> Wt[n][k] bf16 (64x64 LDS transpose, vectorized) -------
// z==3 slice: zero the 8*2048 column-sum buffer (folded launch).
__global__ void wt_kernel(const float* __restrict__ W0, const float* __restrict__ W1,
                          const float* __restrict__ W2, bf16* __restrict__ Wt,
                          float* __restrict__ lbuf) {
  int tid = threadIdx.x;
  if (blockIdx.z == 3) {
    int bid = blockIdx.y * 16 + blockIdx.x;
    if (bid < 64) lbuf[bid * 256 + tid] = 0.f;
    return;
  }
  const float* W = blockIdx.z == 0 ? W0 : blockIdx.z == 1 ? W1 : W2;
  bf16* O = Wt + (size_t)blockIdx.z * 1048576ull;
  __shared__ float t[64][65];
  int n0 = blockIdx.x * 64, k0 = blockIdx.y * 64;
#pragma unroll
  for (int i = 0; i < 4; ++i) {
    int idx = i * 1024 + tid * 4;
    int r = idx >> 6, c = idx & 63;
    float4 v = *(const float4*)(W + (size_t)(k0 + r) * 1024 + n0 + c);
    t[r][c] = v.x; t[r][c + 1] = v.y; t[r][c + 2] = v.z; t[r][c + 3] = v.w;
  }
  __syncthreads();
#pragma unroll
  for (int i = 0; i < 4; ++i) {
    int idx = i * 1024 + tid * 4;
    int r = idx >> 6, c = idx & 63;  // out row n0+r, k cols k0+c..c+3
    alignas(8) bf16 h[4] = {__float2bfloat16(t[c][r]), __float2bfloat16(t[c + 1][r]),
                            __float2bfloat16(t[c + 2][r]), __float2bfloat16(t[c + 3][r])};
    *(unsigned long long*)(O + (size_t)(n0 + r) * 1024 + k0 + c) = *(const unsigned long long*)h;
  }
}

// ------- Vt[e][j] = bf16( V[j][e] / l_j )  (64x64 LDS transpose, vectorized) -------
__global__ void vhat_kernel(const bf16* __restrict__ QKV, const float* __restrict__ l,
                            bf16* __restrict__ Vt) {
  int lb = blockIdx.z;
  const unsigned short* V =
      (const unsigned short*)QKV + ((size_t)lb * 3 + 2) * 2097152ull;  // V slot
  bf16* O = Vt + (size_t)lb * 2097152ull;
  const float* lc = l + lb * 2048;
  __shared__ float t[64][65];
  __shared__ float rl[64];
  int j0 = blockIdx.x * 64, e0 = blockIdx.y * 64;
  int tid = threadIdx.x;
  if (tid < 64) rl[tid] = 1.0f / lc[j0 + tid];
#pragma unroll
  for (int i = 0; i < 4; ++i) {
    int idx = i * 1024 + tid * 4;
    int r = idx >> 6, c = idx & 63;
    ushort4 u = *(const ushort4*)(V + (size_t)(j0 + r) * 1024 + e0 + c);
    t[r][c] = bfbits2f(u.x); t[r][c + 1] = bfbits2f(u.y);
    t[r][c + 2] = bfbits2f(u.z); t[r][c + 3] = bfbits2f(u.w);
  }
  __syncthreads();
#pragma unroll
  for (int i = 0; i < 4; ++i) {
    int idx = i * 1024 + tid * 4;
    int r = idx >> 6, c = idx & 63;  // out row e0+r, cols j0+c..c+3
    alignas(8) bf16 h[4] = {
        __float2bfloat16(t[c][r] * rl[c]), __float2bfloat16(t[c + 1][r] * rl[c + 1]),
        __float2bfloat16(t[c + 2][r] * rl[c + 2]), __float2bfloat16(t[c + 3][r] * rl[c + 3])};
    *(unsigned long long*)(O + (size_t)(e0 + r) * 2048 + j0 + c) = *(const unsigned long long*)h;
  }
}

// ---------------- 256x256 8-phase GEMM ----------------
// One phase: ds-read one 64x32 C-quadrant's fragments, issue 1 half-tile
// stage, barrier, setprio(1), 16 MFMA, setprio(0), [vmcnt(4)], barrier.
template <int QA, int QB>
__device__ __forceinline__ void phase256(
    bf16 (*As)[256][64], bf16 (*Bs)[256][64], const int buf,
    f32x4 (&acc)[2][2][4][2], const int wm, const int wn, const int fm, const int kg,
    const bf16* gsrc, const int gld, bf16* ldst,
    const int srow, const int scg, const int scl, const bool vm4) {
  short8 af[2][4], bw[2][2];
#pragma unroll
  for (int i = 0; i < 4; ++i) {
    const int row = QA * 128 + wm * 64 + i * 16 + fm;
    const int x = row & 7;
#pragma unroll
    for (int ks = 0; ks < 2; ++ks)
      af[ks][i] = *(const short8*)(&As[buf][row][((ks * 4 + kg) ^ x) * 8]);
  }
#pragma unroll
  for (int j = 0; j < 2; ++j) {
    const int col = QB * 128 + wn * 32 + j * 16 + fm;
    const int x = col & 7;
#pragma unroll
    for (int ks = 0; ks < 2; ++ks)
      bw[ks][j] = *(const short8*)(&Bs[buf][col][((ks * 4 + kg) ^ x) * 8]);
  }
  // stage one half-tile (2 x global_load_lds dwordx4; dest linear, src pre-swizzled)
#pragma unroll
  for (int r = 0; r < 2; ++r)
    __builtin_amdgcn_global_load_lds(
        (const __attribute__((address_space(1))) void*)(gsrc + (size_t)(r * 64 + srow) * gld + scg),
        (__attribute__((address_space(3))) void*)(ldst + (r * 64 + srow) * 64 + scl), 16, 0, 0);
  __builtin_amdgcn_s_barrier();
  // compiler inserts fine-grained lgkmcnt before first MFMA use
  __builtin_amdgcn_s_setprio(1);
#pragma unroll
  for (int ks = 0; ks < 2; ++ks)
#pragma unroll
    for (int i = 0; i < 4; ++i)
#pragma unroll
      for (int j = 0; j < 2; ++j)
        acc[QA][QB][i][j] = __builtin_amdgcn_mfma_f32_16x16x32_bf16(
            af[ks][i], bw[ks][j], acc[QA][QB][i][j], 0, 0, 0);
  __builtin_amdgcn_s_setprio(0);
  if (vm4) {
    asm volatile("s_waitcnt vmcnt(4)" ::: "memory");
    __builtin_amdgcn_sched_barrier(0);
  }
  __builtin_amdgcn_s_barrier();
}

// EPI: 0 = bf16 store (QKV), 1 = P=exp(acc/32) causal-masked + fused column-sum,
//      2 = fp32 store (PV out). VARK: K = (by+1)*256, y reversed (long-K first).
template <int EPI, bool VARK>
__device__ __forceinline__ void gemm256_body(
    const bf16* __restrict__ A, const bf16* __restrict__ B, void* __restrict__ Cv,
    int lda, int ldb, int ldc, int Kin, int zdivA, int zmodB,
    ull sA, ull sB, ull sC, float* __restrict__ lptr) {
  const unsigned gx = gridDim.x, gy = gridDim.y;
  const unsigned per_z = gx * gy;
  const unsigned total = per_z * gridDim.z;
  unsigned id = blockIdx.x + gx * (blockIdx.y + gy * blockIdx.z);
  unsigned lid = (id & 7) * (total >> 3) + (id >> 3);
  const unsigned bz = lid / per_z;
  unsigned rem = lid - bz * per_z;
  constexpr unsigned H = 8;
  const unsigned band = rem / (gx * H);
  const unsigned w = rem - band * (gx * H);
  const unsigned bx = w / H;
  const unsigned by_raw = band * H + (w - bx * H);
  const unsigned by = VARK ? (gy - 1 - by_raw) : by_raw;

  if constexpr (EPI == 1) {
    if (bx > by) return;  // strictly-upper score tile: skip (before any barrier)
  }
  const int z = (int)bz;
  A += (ull)(z / zdivA) * sA;
  B += (ull)(z % zmodB) * sB;
  const int K = VARK ? (int)(by + 1) * 256 : Kin;
  const int NT = K >> 6, NU = NT >> 1;  // K-tiles of 64; iterations of 2 tiles

  alignas(16) __shared__ bf16 As[2][256][64];  // 64KB
  alignas(16) __shared__ bf16 Bs[2][256][64];  // 64KB

  const int tid = threadIdx.x, wave = tid >> 6, lane = tid & 63;
  const int wm = wave >> 2, wn = wave & 3;       // 2M x 4N wave grid
  const int fm = lane & 15, kg = lane >> 4;
  const int m0 = (int)by * 256, n0 = (int)bx * 256;
  const int srow = tid >> 3;                     // staging row 0..63 per round
  const int scg = ((tid & 7) ^ (srow & 7)) * 8;  // swizzled GLOBAL chunk (elements)
  const int scl = (tid & 7) * 8;                 // linear LDS chunk

  const bf16* A0r = A + (size_t)m0 * lda;        // rows m0..m0+127
  const bf16* A1r = A0r + (size_t)128 * lda;     // rows m0+128..m0+255
  const bf16* B0r = B + (size_t)n0 * ldb;
  const bf16* B1r = B0r + (size_t)128 * ldb;

  f32x4 acc[2][2][4][2];
#pragma unroll
  for (int qa = 0; qa < 2; ++qa)
#pragma unroll
    for (int qb = 0; qb < 2; ++qb)
#pragma unroll
      for (int i = 0; i < 4; ++i)
#pragma unroll
        for (int j = 0; j < 2; ++j) acc[qa][qb][i][j] = (f32x4){0.f, 0.f, 0.f, 0.f};

  auto stage = [&](const bf16* g, int gld, bf16* l) {
#pragma unroll
    for (int r = 0; r < 2; ++r)
      __builtin_amdgcn_global_load_lds(
          (const __attribute__((address_space(1))) void*)(g + (size_t)(r * 64 + srow) * gld + scg),
          (__attribute__((address_space(3))) void*)(l + (r * 64 + srow) * 64 + scl), 16, 0, 0);
  };

  // prologue: stage A0(0),B0(0),A1(0),B1(0),A0(1),B0(1); wait tile0 landed (4 in flight)
  stage(A0r, lda, &As[0][0][0]);
  stage(B0r, ldb, &Bs[0][0][0]);
  stage(A1r, lda, &As[0][128][0]);
  stage(B1r, ldb, &Bs[0][128][0]);
  stage(A0r + 64, lda, &As[1][0][0]);
  stage(B0r + 64, ldb, &Bs[1][0][0]);
  asm volatile("s_waitcnt vmcnt(4)" ::: "memory");
  __builtin_amdgcn_sched_barrier(0);
  __builtin_amdgcn_s_barrier();

  for (int u = 0; u < NU; ++u) {
    const int t = 2 * u;
    const int k1 = (t + 1) * 64;
    const int k2 = (t + 2 < NT ? t + 2 : NT - 1) * 64;  // clamp: keep vmcnt uniform,
    const int k3 = (t + 3 < NT ? t + 3 : NT - 1) * 64;  // slots never consumed
    phase256<0, 0>(As, Bs, 0, acc, wm, wn, fm, kg, A1r + k1, lda, &As[1][128][0], srow, scg, scl, false);
    phase256<0, 1>(As, Bs, 0, acc, wm, wn, fm, kg, B1r + k1, ldb, &Bs[1][128][0], srow, scg, scl, false);
    phase256<1, 0>(As, Bs, 0, acc, wm, wn, fm, kg, A0r + k2, lda, &As[0][0][0],   srow, scg, scl, false);
    phase256<1, 1>(As, Bs, 0, acc, wm, wn, fm, kg, B0r + k2, ldb, &Bs[0][0][0],   srow, scg, scl, true);
    phase256<0, 0>(As, Bs, 1, acc, wm, wn, fm, kg, A1r + k2, lda, &As[0][128][0], srow, scg, scl, false);
    phase256<0, 1>(As, Bs, 1, acc, wm, wn, fm, kg, B1r + k2, ldb, &Bs[0][128][0], srow, scg, scl, false);
    phase256<1, 0>(As, Bs, 1, acc, wm, wn, fm, kg, A0r + k3, lda, &As[1][0][0],   srow, scg, scl, false);
    phase256<1, 1>(As, Bs, 1, acc, wm, wn, fm, kg, B0r + k3, ldb, &Bs[1][0][0],   srow, scg, scl, true);
  }

  // epilogue — C/D layout: col = lane&15, row = (lane>>4)*4 + reg
  const int cr = kg * 4, cc = fm;
  if constexpr (EPI == 2) {
    float* C = (float*)Cv + (ull)z * sC;
#pragma unroll
    for (int qa = 0; qa < 2; ++qa)
#pragma unroll
      for (int qb = 0; qb < 2; ++qb)
#pragma unroll
        for (int i = 0; i < 4; ++i)
#pragma unroll
          for (int j = 0; j < 2; ++j)
#pragma unroll
            for (int r = 0; r < 4; ++r)
              C[(size_t)(m0 + qa * 128 + wm * 64 + i * 16 + cr + r) * ldc +
                (n0 + qb * 128 + wn * 32 + j * 16 + cc)] = acc[qa][qb][i][j][r];
  } else if constexpr (EPI == 0) {
    bf16* C = (bf16*)Cv + (ull)z * sC;
#pragma unroll
    for (int qa = 0; qa < 2; ++qa)
#pragma unroll
      for (int qb = 0; qb < 2; ++qb)
#pragma unroll
        for (int i = 0; i < 4; ++i)
#pragma unroll
          for (int j = 0; j < 2; ++j)
#pragma unroll
            for (int r = 0; r < 4; ++r)
              C[(size_t)(m0 + qa * 128 + wm * 64 + i * 16 + cr + r) * ldc +
                (n0 + qb * 128 + wn * 32 + j * 16 + cc)] =
                  __float2bfloat16(acc[qa][qb][i][j][r]);
  } else {
    // EPI == 1: P = exp(acc/32) causal-masked, plus fused column sums into lptr
    bf16* C = (bf16*)Cv + (ull)z * sC;
    float colpart[2][2] = {{0.f, 0.f}, {0.f, 0.f}};
#pragma unroll
    for (int qa = 0; qa < 2; ++qa)
#pragma unroll
      for (int qb = 0; qb < 2; ++qb)
#pragma unroll
        for (int i = 0; i < 4; ++i)
#pragma unroll
          for (int j = 0; j < 2; ++j)
#pragma unroll
            for (int r = 0; r < 4; ++r) {
              int gm = m0 + qa * 128 + wm * 64 + i * 16 + cr + r;
              int gn = n0 + qb * 128 + wn * 32 + j * 16 + cc;
              float s = acc[qa][qb][i][j][r] * 0.03125f;  // 1/sqrt(1024)
              float p = (gn <= gm) ? __expf(s) : 0.f;     // causal: j<=i, else exact 0
              colpart[qb][j] += p;
              C[(size_t)gm * ldc + gn] = __float2bfloat16(p);
            }
    float* lbase = lptr + (size_t)z * 2048;
#pragma unroll
    for (int qb = 0; qb < 2; ++qb)
#pragma unroll
      for (int j = 0; j < 2; ++j) {
        float s = colpart[qb][j];
        s += __shfl_xor(s, 16);
        s += __shfl_xor(s, 32);
        if (lane < 16)
          atomicAdd(&lbase[n0 + qb * 128 + wn * 32 + j * 16 + lane], s);
      }
  }
}

// Distinct kernel names so rocprof's per-dispatch table separates the three GEMMs.
__global__ __launch_bounds__(512, 2) void gemm_qkv(
    const bf16* __restrict__ A, const bf16* __restrict__ B, void* __restrict__ Cv,
    int lda, int ldb, int ldc, int Kin, int zdivA, int zmodB,
    ull sA, ull sB, ull sC) {
  gemm256_body<0, false>(A, B, Cv, lda, ldb, ldc, Kin, zdivA, zmodB, sA, sB, sC, nullptr);
}
__global__ __launch_bounds__(512, 2) void gemm_scores(
    const bf16* __restrict__ A, const bf16* __restrict__ B, void* __restrict__ Cv,
    int lda, int ldb, int ldc, int Kin, int zdivA, int zmodB,
    ull sA, ull sB, ull sC, float* __restrict__ lptr) {
  gemm256_body<1, false>(A, B, Cv, lda, ldb, ldc, Kin, zdivA, zmodB, sA, sB, sC, lptr);
}
__global__ __launch_bounds__(512, 2) void gemm_pv(
    const bf16* __restrict__ A, const bf16* __restrict__ B, void* __restrict__ Cv,
    int lda, int ldb, int ldc, int Kin, int zdivA, int zmodB,
    ull sA, ull sB, ull sC) {
  gemm256_body<2, true>(A, B, Cv, lda, ldb, ldc, Kin, zdivA, zmodB, sA, sB, sC, nullptr);
}

// ---------------- host ----------------
extern "C" void kernel_launch(void* const* d_in, const int* in_sizes, int n_in,
                              void* d_out, int out_size, void* d_ws, size_t ws_size,
                              hipStream_t stream) {
  const float* x = (const float*)d_in[0];
  const float* Wq = (const float*)d_in[1];
  const float* Wk = (const float*)d_in[2];
  const float* Wv = (const float*)d_in[3];
  float* out = (float*)d_out;

  constexpr unsigned long long X_EL = 2048ull * 1024;  // per batch
  constexpr unsigned long long QKV_EL = 3ull * X_EL;
  constexpr unsigned long long P_EL = 2048ull * 2048;
  constexpr unsigned long long VT_EL = 1024ull * 2048;
  constexpr unsigned long long WT_B = 3ull * 1024 * 1024 * 2;
  constexpr unsigned long long LB_B = 8ull * 2048 * 4;  // column sums, all 8 batches
  constexpr unsigned long long PER_B = 2 * (X_EL + QKV_EL + P_EL + VT_EL);

  size_t NB = 1;
  for (size_t nb : {(size_t)8, (size_t)4, (size_t)2})
    if (WT_B + LB_B + nb * PER_B <= ws_size) { NB = nb; break; }

  char* p = (char*)d_ws;
  bf16* Wt = (bf16*)p;   p += WT_B;
  float* lbuf = (float*)p; p += LB_B;
  bf16* Xb = (bf16*)p;   p += 2 * NB * X_EL;
  bf16* QKV = (bf16*)p;  p += 2 * NB * QKV_EL;
  bf16* P = (bf16*)p;    p += 2 * NB * P_EL;
  bf16* Vt = (bf16*)p;

  // weight transpose + zero lbuf (z==3 slice)
  wt_kernel<<<dim3(16, 16, 4), 256, 0, stream>>>(Wq, Wk, Wv, Wt, lbuf);

  for (size_t b0 = 0; b0 < 8; b0 += NB) {
    // x chunk -> bf16
    cvt_kernel<<<dim3((unsigned)(NB * 2048)), 256, 0, stream>>>(x + b0 * X_EL, Xb);
    // Q,K,V = X @ W  (z = lb*3 + weight)
    gemm_qkv<<<dim3(4, 8, (unsigned)(NB * 3)), 512, 0, stream>>>(
        Xb, Wt, QKV, 1024, 1024, 1024, 1024, 3, 3, X_EL, 1048576ull, X_EL);
    // P = exp(QK^T/32) lower-triangle tiles, causal-masked, fused column sums
    gemm_scores<<<dim3(8, 8, (unsigned)NB), 512, 0, stream>>>(
        QKV, QKV + X_EL, P, 1024, 1024, 2048, 1024, 1, 1 << 30, QKV_EL, QKV_EL, P_EL,
        lbuf + b0 * 2048);
    vhat_kernel<<<dim3(32, 16, (unsigned)NB), 256, 0, stream>>>(QKV, lbuf + b0 * 2048, Vt);
    // out = P @ Vt^T, K stops at diagonal tile
    gemm_pv<<<dim3(4, 8, (unsigned)NB), 512, 0, stream>>>(
        P, Vt, out + b0 * X_EL, 2048, 2048, 1024, 0, 1, 1 << 30, P_EL, VT_EL, X_EL);
  }
}

// Round 2
// 378.618 us; speedup vs baseline: 1.0696x; 1.0696x over previous
//
#include <hip/hip_runtime.h>
#include <hip/hip_bf16.h>

// CausalAttention: q=xWq,k=xWk,v=xWv; S=qk^T; causal mask (j>i -> -inf);
// softmax over AXIS=1 (query axis, COLUMN-wise over i) of S/32; out = W @ v.
// Strategy: P[i,j]=exp(s_ij/32), l_j=sum_{i>=j} P (fused in P-GEMM epilogue),
// fold 1/l_j into V rows -> out = P @ (V/l)^T.
// R7 (fix of R6's 8-phase regression, MfmaUtil 32.5%):
//  (a) A-fragment register reuse: consume order per K-tile is
//      (QA,QB)=(0,0),(0,1),(1,0),(1,1); A-frags (8 ds_read_b128) loaded only on
//      QB==0 phases and HELD across the QB==1 phase. ds_reads/wave/tile 48->32
//      (R6 re-read A+B every phase -> LDS read pipe was the critical path).
//  (b) Derived per-phase counted waits (vmcnt retires in order, monotone):
//      stage order s1..s8 = A1(t+1),B1(t+1),A0(t+2),B0(t+2),A1(t+2),B1(t+2),
//      A0(t+3),B0(t+3). Dep analysis gives waits end-ph1 vmcnt(6),
//      end-ph4 vmcnt(8), end-ph5 vmcnt(6), end-ph8 vmcnt(8): every half gets
//      >=3 phases (~500cy) to land (R6's vmcnt(4)@ph4/8 gave only 2 phases ->
//      stalled on HBM latency). Never vmcnt(0) in-loop. Out-of-range K-tiles
//      are SOURCE-CLAMPED (never skipped) so per-wave counts stay uniform.
// Geometry: 256x256 tile, BK=64, 8 waves (2Mx4N), 512 thr, 128KB LDS
// (2 dbuf x {A,B} x 256x64), 1 block/CU. Phase = one 64x32 C-quadrant x K=64:
// [ds_read frags; stage 1 half-tile (2x global_load_lds x16B); s_barrier;
//  setprio(1); 16 MFMA; setprio(0); (vmcnt N); s_barrier].
// LDS XOR swizzle kept (0 bank conflicts): phys 16B chunk = logical ^ (row&7);
// global source pre-swizzled so global_load_lds dest stays linear.
// XCD swizzle + banded traversal kept (R4/R5).

using bf16 = __hip_bfloat16;
typedef __attribute__((ext_vector_type(8))) short short8;
typedef __attribute__((ext_vector_type(4))) float f32x4;
typedef unsigned long long ull;

__device__ __forceinline__ float bfbits2f(unsigned short u) {
  return __uint_as_float((unsigned)u << 16);
}

// ---------------- fp32 -> bf16 convert (x4 per thread) ----------------
__global__ void cvt_kernel(const float* __restrict__ in, bf16* __restrict__ out) {
  size_t i = ((size_t)blockIdx.x * 256 + threadIdx.x) * 4;
  float4 v = *(const float4*)(in + i);
  alignas(8) bf16 h[4] = {__float2bfloat16(v.x), __float2bfloat16(v.y),
                          __float2bfloat16(v.z), __float2bfloat16(v.w)};
  *(unsigned long long*)(out + i) = *(const unsigned long long*)h;
}

// ------- W[k][n] fp32 -> Wt[n][k] bf16 (64x64 LDS transpose, vectorized) -------
// z==3 slice: zero the 8*2048 column-sum buffer (folded launch).
__global__ void wt_kernel(const float* __restrict__ W0, const float* __restrict__ W1,
                          const float* __restrict__ W2, bf16* __restrict__ Wt,
                          float* __restrict__ lbuf) {
  int tid = threadIdx.x;
  if (blockIdx.z == 3) {
    int bid = blockIdx.y * 16 + blockIdx.x;
    if (bid < 64) lbuf[bid * 256 + tid] = 0.f;
    return;
  }
  const float* W = blockIdx.z == 0 ? W0 : blockIdx.z == 1 ? W1 : W2;
  bf16* O = Wt + (size_t)blockIdx.z * 1048576ull;
  __shared__ float t[64][65];
  int n0 = blockIdx.x * 64, k0 = blockIdx.y * 64;
#pragma unroll
  for (int i = 0; i < 4; ++i) {
    int idx = i * 1024 + tid * 4;
    int r = idx >> 6, c = idx & 63;
    float4 v = *(const float4*)(W + (size_t)(k0 + r) * 1024 + n0 + c);
    t[r][c] = v.x; t[r][c + 1] = v.y; t[r][c + 2] = v.z; t[r][c + 3] = v.w;
  }
  __syncthreads();
#pragma unroll
  for (int i = 0; i < 4; ++i) {
    int idx = i * 1024 + tid * 4;
    int r = idx >> 6, c = idx & 63;  // out row n0+r, k cols k0+c..c+3
    alignas(8) bf16 h[4] = {__float2bfloat16(t[c][r]), __float2bfloat16(t[c + 1][r]),
                            __float2bfloat16(t[c + 2][r]), __float2bfloat16(t[c + 3][r])};
    *(unsigned long long*)(O + (size_t)(n0 + r) * 1024 + k0 + c) = *(const unsigned long long*)h;
  }
}

// ------- Vt[e][j] = bf16( V[j][e] / l_j )  (64x64 LDS transpose, vectorized) -------
__global__ void vhat_kernel(const bf16* __restrict__ QKV, const float* __restrict__ l,
                            bf16* __restrict__ Vt) {
  int lb = blockIdx.z;
  const unsigned short* V =
      (const unsigned short*)QKV + ((size_t)lb * 3 + 2) * 2097152ull;  // V slot
  bf16* O = Vt + (size_t)lb * 2097152ull;
  const float* lc = l + lb * 2048;
  __shared__ float t[64][65];
  __shared__ float rl[64];
  int j0 = blockIdx.x * 64, e0 = blockIdx.y * 64;
  int tid = threadIdx.x;
  if (tid < 64) rl[tid] = 1.0f / lc[j0 + tid];
#pragma unroll
  for (int i = 0; i < 4; ++i) {
    int idx = i * 1024 + tid * 4;
    int r = idx >> 6, c = idx & 63;
    ushort4 u = *(const ushort4*)(V + (size_t)(j0 + r) * 1024 + e0 + c);
    t[r][c] = bfbits2f(u.x); t[r][c + 1] = bfbits2f(u.y);
    t[r][c + 2] = bfbits2f(u.z); t[r][c + 3] = bfbits2f(u.w);
  }
  __syncthreads();
#pragma unroll
  for (int i = 0; i < 4; ++i) {
    int idx = i * 1024 + tid * 4;
    int r = idx >> 6, c = idx & 63;  // out row e0+r, cols j0+c..c+3
    alignas(8) bf16 h[4] = {
        __float2bfloat16(t[c][r] * rl[c]), __float2bfloat16(t[c + 1][r] * rl[c + 1]),
        __float2bfloat16(t[c + 2][r] * rl[c + 2]), __float2bfloat16(t[c + 3][r] * rl[c + 3])};
    *(unsigned long long*)(O + (size_t)(e0 + r) * 2048 + j0 + c) = *(const unsigned long long*)h;
  }
}

// ---------------- 256x256 8-phase GEMM ----------------
// Phase: [QB==0: ds-read A-frags (8)] ds-read B-frags (4); stage 1 half-tile;
// s_barrier; setprio(1); 16 MFMA; setprio(0); [vmcnt(VMN)]; s_barrier.
// VMN: -1 = no wait.
template <int QA, int QB, int VMN>
__device__ __forceinline__ void phase256(
    bf16 (*As)[256][64], bf16 (*Bs)[256][64], const int buf,
    short8 (&af)[2][4], f32x4 (&acc)[2][2][4][2],
    const int wm, const int wn, const int fm, const int kg,
    const bf16* gsrc, const int gld, bf16* ldst,
    const int srow, const int scg, const int scl) {
  if constexpr (QB == 0) {
#pragma unroll
    for (int i = 0; i < 4; ++i) {
      const int row = QA * 128 + wm * 64 + i * 16 + fm;
      const int x = row & 7;
#pragma unroll
      for (int ks = 0; ks < 2; ++ks)
        af[ks][i] = *(const short8*)(&As[buf][row][((ks * 4 + kg) ^ x) * 8]);
    }
  }
  short8 bw[2][2];
#pragma unroll
  for (int j = 0; j < 2; ++j) {
    const int col = QB * 128 + wn * 32 + j * 16 + fm;
    const int x = col & 7;
#pragma unroll
    for (int ks = 0; ks < 2; ++ks)
      bw[ks][j] = *(const short8*)(&Bs[buf][col][((ks * 4 + kg) ^ x) * 8]);
  }
  // stage one half-tile (2 x global_load_lds dwordx4; dest linear, src pre-swizzled)
#pragma unroll
  for (int r = 0; r < 2; ++r)
    __builtin_amdgcn_global_load_lds(
        (const __attribute__((address_space(1))) void*)(gsrc + (size_t)(r * 64 + srow) * gld + scg),
        (__attribute__((address_space(3))) void*)(ldst + (r * 64 + srow) * 64 + scl), 16, 0, 0);
  __builtin_amdgcn_s_barrier();
  // compiler inserts fine-grained lgkmcnt before first MFMA use
  __builtin_amdgcn_s_setprio(1);
#pragma unroll
  for (int ks = 0; ks < 2; ++ks)
#pragma unroll
    for (int i = 0; i < 4; ++i)
#pragma unroll
      for (int j = 0; j < 2; ++j)
        acc[QA][QB][i][j] = __builtin_amdgcn_mfma_f32_16x16x32_bf16(
            af[ks][i], bw[ks][j], acc[QA][QB][i][j], 0, 0, 0);
  __builtin_amdgcn_s_setprio(0);
  if constexpr (VMN == 6) {
    asm volatile("s_waitcnt vmcnt(6)" ::: "memory");
    __builtin_amdgcn_sched_barrier(0);
  } else if constexpr (VMN == 8) {
    asm volatile("s_waitcnt vmcnt(8)" ::: "memory");
    __builtin_amdgcn_sched_barrier(0);
  }
  __builtin_amdgcn_s_barrier();
}

// EPI: 0 = bf16 store (QKV), 1 = P=exp(acc/32) causal-masked + fused column-sum,
//      2 = fp32 store (PV out). VARK: K = (by+1)*256, y reversed (long-K first).
template <int EPI, bool VARK>
__device__ __forceinline__ void gemm256_body(
    const bf16* __restrict__ A, const bf16* __restrict__ B, void* __restrict__ Cv,
    int lda, int ldb, int ldc, int Kin, int zdivA, int zmodB,
    ull sA, ull sB, ull sC, float* __restrict__ lptr) {
  const unsigned gx = gridDim.x, gy = gridDim.y;
  const unsigned per_z = gx * gy;
  const unsigned total = per_z * gridDim.z;
  unsigned id = blockIdx.x + gx * (blockIdx.y + gy * blockIdx.z);
  unsigned lid = (id & 7) * (total >> 3) + (id >> 3);
  const unsigned bz = lid / per_z;
  unsigned rem = lid - bz * per_z;
  constexpr unsigned H = 8;
  const unsigned band = rem / (gx * H);
  const unsigned w = rem - band * (gx * H);
  const unsigned bx = w / H;
  const unsigned by_raw = band * H + (w - bx * H);
  const unsigned by = VARK ? (gy - 1 - by_raw) : by_raw;

  if constexpr (EPI == 1) {
    if (bx > by) return;  // strictly-upper score tile: skip (before any barrier)
  }
  const int z = (int)bz;
  A += (ull)(z / zdivA) * sA;
  B += (ull)(z % zmodB) * sB;
  const int K = VARK ? (int)(by + 1) * 256 : Kin;
  const int NT = K >> 6, NU = NT >> 1;  // K-tiles of 64; iterations of 2 tiles

  alignas(16) __shared__ bf16 As[2][256][64];  // 64KB
  alignas(16) __shared__ bf16 Bs[2][256][64];  // 64KB

  const int tid = threadIdx.x, wave = tid >> 6, lane = tid & 63;
  const int wm = wave >> 2, wn = wave & 3;       // 2M x 4N wave grid
  const int fm = lane & 15, kg = lane >> 4;
  const int m0 = (int)by * 256, n0 = (int)bx * 256;
  const int srow = tid >> 3;                     // staging row 0..63 per round
  const int scg = ((tid & 7) ^ (srow & 7)) * 8;  // swizzled GLOBAL chunk (elements)
  const int scl = (tid & 7) * 8;                 // linear LDS chunk

  const bf16* A0r = A + (size_t)m0 * lda;        // rows m0..m0+127
  const bf16* A1r = A0r + (size_t)128 * lda;     // rows m0+128..m0+255
  const bf16* B0r = B + (size_t)n0 * ldb;
  const bf16* B1r = B0r + (size_t)128 * ldb;

  f32x4 acc[2][2][4][2];
#pragma unroll
  for (int qa = 0; qa < 2; ++qa)
#pragma unroll
    for (int qb = 0; qb < 2; ++qb)
#pragma unroll
      for (int i = 0; i < 4; ++i)
#pragma unroll
        for (int j = 0; j < 2; ++j) acc[qa][qb][i][j] = (f32x4){0.f, 0.f, 0.f, 0.f};

  short8 af[2][4];  // A-fragments held across the two QB phases of each QA

  auto stage = [&](const bf16* g, int gld, bf16* l) {
#pragma unroll
    for (int r = 0; r < 2; ++r)
      __builtin_amdgcn_global_load_lds(
          (const __attribute__((address_space(1))) void*)(g + (size_t)(r * 64 + srow) * gld + scg),
          (__attribute__((address_space(3))) void*)(l + (r * 64 + srow) * 64 + scl), 16, 0, 0);
  };

  // prologue: stage halves #1..#6 = A0(0),B0(0),A1(0),B1(0),A0(1),B0(1).
  // ph1 of iter0 reads #1,#2 -> need #2 landed -> allow #3..#6 out -> vmcnt(8).
  stage(A0r, lda, &As[0][0][0]);
  stage(B0r, ldb, &Bs[0][0][0]);
  stage(A1r, lda, &As[0][128][0]);
  stage(B1r, ldb, &Bs[0][128][0]);
  stage(A0r + 64, lda, &As[1][0][0]);
  stage(B0r + 64, ldb, &Bs[1][0][0]);
  asm volatile("s_waitcnt vmcnt(8)" ::: "memory");
  __builtin_amdgcn_sched_barrier(0);
  __builtin_amdgcn_s_barrier();

  // steady state (tiles t=2u in buf0 ph1-4, t+1 in buf1 ph5-8):
  //   s1:A1(t+1)->buf1  s2:B1(t+1)->buf1  s3:A0(t+2)->buf0  s4:B0(t+2)->buf0
  //   s5:A1(t+2)->buf0  s6:B1(t+2)->buf0  s7:A0(t+3)->buf1  s8:B0(t+3)->buf1
  // waits: end-ph1 vmcnt(6) [guards ph2's B1(t), staged prev-s6]
  //        end-ph4 vmcnt(8) [guards ph5's A0/B0(t+1), staged prev-s7/s8]
  //        end-ph5 vmcnt(6) [guards ph6's B1(t+1), staged s2]
  //        end-ph8 vmcnt(8) [guards next-ph1's A0/B0(t+2), staged s3/s4]
  for (int u = 0; u < NU; ++u) {
    const int t = 2 * u;
    const int k1 = (t + 1) * 64;
    const int k2 = (t + 2 < NT ? t + 2 : NT - 1) * 64;  // clamp: keep vmcnt uniform,
    const int k3 = (t + 3 < NT ? t + 3 : NT - 1) * 64;  // slots never consumed
    phase256<0, 0, 6>(As, Bs, 0, af, acc, wm, wn, fm, kg, A1r + k1, lda, &As[1][128][0], srow, scg, scl);
    phase256<0, 1, -1>(As, Bs, 0, af, acc, wm, wn, fm, kg, B1r + k1, ldb, &Bs[1][128][0], srow, scg, scl);
    phase256<1, 0, -1>(As, Bs, 0, af, acc, wm, wn, fm, kg, A0r + k2, lda, &As[0][0][0],   srow, scg, scl);
    phase256<1, 1, 8>(As, Bs, 0, af, acc, wm, wn, fm, kg, B0r + k2, ldb, &Bs[0][0][0],   srow, scg, scl);
    phase256<0, 0, 6>(As, Bs, 1, af, acc, wm, wn, fm, kg, A1r + k2, lda, &As[0][128][0], srow, scg, scl);
    phase256<0, 1, -1>(As, Bs, 1, af, acc, wm, wn, fm, kg, B1r + k2, ldb, &Bs[0][128][0], srow, scg, scl);
    phase256<1, 0, -1>(As, Bs, 1, af, acc, wm, wn, fm, kg, A0r + k3, lda, &As[1][0][0],   srow, scg, scl);
    phase256<1, 1, 8>(As, Bs, 1, af, acc, wm, wn, fm, kg, B0r + k3, ldb, &Bs[1][0][0],   srow, scg, scl);
  }

  // epilogue — C/D layout: col = lane&15, row = (lane>>4)*4 + reg
  const int cr = kg * 4, cc = fm;
  if constexpr (EPI == 2) {
    float* C = (float*)Cv + (ull)z * sC;
#pragma unroll
    for (int qa = 0; qa < 2; ++qa)
#pragma unroll
      for (int qb = 0; qb < 2; ++qb)
#pragma unroll
        for (int i = 0; i < 4; ++i)
#pragma unroll
          for (int j = 0; j < 2; ++j)
#pragma unroll
            for (int r = 0; r < 4; ++r)
              C[(size_t)(m0 + qa * 128 + wm * 64 + i * 16 + cr + r) * ldc +
                (n0 + qb * 128 + wn * 32 + j * 16 + cc)] = acc[qa][qb][i][j][r];
  } else if constexpr (EPI == 0) {
    bf16* C = (bf16*)Cv + (ull)z * sC;
#pragma unroll
    for (int qa = 0; qa < 2; ++qa)
#pragma unroll
      for (int qb = 0; qb < 2; ++qb)
#pragma unroll
        for (int i = 0; i < 4; ++i)
#pragma unroll
          for (int j = 0; j < 2; ++j)
#pragma unroll
            for (int r = 0; r < 4; ++r)
              C[(size_t)(m0 + qa * 128 + wm * 64 + i * 16 + cr + r) * ldc +
                (n0 + qb * 128 + wn * 32 + j * 16 + cc)] =
                  __float2bfloat16(acc[qa][qb][i][j][r]);
  } else {
    // EPI == 1: P = exp(acc/32) causal-masked, plus fused column sums into lptr
    bf16* C = (bf16*)Cv + (ull)z * sC;
    float colpart[2][2] = {{0.f, 0.f}, {0.f, 0.f}};
#pragma unroll
    for (int qa = 0; qa < 2; ++qa)
#pragma unroll
      for (int qb = 0; qb < 2; ++qb)
#pragma unroll
        for (int i = 0; i < 4; ++i)
#pragma unroll
          for (int j = 0; j < 2; ++j)
#pragma unroll
            for (int r = 0; r < 4; ++r) {
              int gm = m0 + qa * 128 + wm * 64 + i * 16 + cr + r;
              int gn = n0 + qb * 128 + wn * 32 + j * 16 + cc;
              float s = acc[qa][qb][i][j][r] * 0.03125f;  // 1/sqrt(1024)
              float p = (gn <= gm) ? __expf(s) : 0.f;     // causal: j<=i, else exact 0
              colpart[qb][j] += p;
              C[(size_t)gm * ldc + gn] = __float2bfloat16(p);
            }
    float* lbase = lptr + (size_t)z * 2048;
#pragma unroll
    for (int qb = 0; qb < 2; ++qb)
#pragma unroll
      for (int j = 0; j < 2; ++j) {
        float s = colpart[qb][j];
        s += __shfl_xor(s, 16);
        s += __shfl_xor(s, 32);
        if (lane < 16)
          atomicAdd(&lbase[n0 + qb * 128 + wn * 32 + j * 16 + lane], s);
      }
  }
}

// Distinct kernel names so rocprof's per-dispatch table separates the three GEMMs.
__global__ __launch_bounds__(512, 2) void gemm_qkv(
    const bf16* __restrict__ A, const bf16* __restrict__ B, void* __restrict__ Cv,
    int lda, int ldb, int ldc, int Kin, int zdivA, int zmodB,
    ull sA, ull sB, ull sC) {
  gemm256_body<0, false>(A, B, Cv, lda, ldb, ldc, Kin, zdivA, zmodB, sA, sB, sC, nullptr);
}
__global__ __launch_bounds__(512, 2) void gemm_scores(
    const bf16* __restrict__ A, const bf16* __restrict__ B, void* __restrict__ Cv,
    int lda, int ldb, int ldc, int Kin, int zdivA, int zmodB,
    ull sA, ull sB, ull sC, float* __restrict__ lptr) {
  gemm256_body<1, false>(A, B, Cv, lda, ldb, ldc, Kin, zdivA, zmodB, sA, sB, sC, lptr);
}
__global__ __launch_bounds__(512, 2) void gemm_pv(
    const bf16* __restrict__ A, const bf16* __restrict__ B, void* __restrict__ Cv,
    int lda, int ldb, int ldc, int Kin, int zdivA, int zmodB,
    ull sA, ull sB, ull sC) {
  gemm256_body<2, true>(A, B, Cv, lda, ldb, ldc, Kin, zdivA, zmodB, sA, sB, sC, nullptr);
}

// ---------------- host ----------------
extern "C" void kernel_launch(void* const* d_in, const int* in_sizes, int n_in,
                              void* d_out, int out_size, void* d_ws, size_t ws_size,
                              hipStream_t stream) {
  const float* x = (const float*)d_in[0];
  const float* Wq = (const float*)d_in[1];
  const float* Wk = (const float*)d_in[2];
  const float* Wv = (const float*)d_in[3];
  float* out = (float*)d_out;

  constexpr unsigned long long X_EL = 2048ull * 1024;  // per batch
  constexpr unsigned long long QKV_EL = 3ull * X_EL;
  constexpr unsigned long long P_EL = 2048ull * 2048;
  constexpr unsigned long long VT_EL = 1024ull * 2048;
  constexpr unsigned long long WT_B = 3ull * 1024 * 1024 * 2;
  constexpr unsigned long long LB_B = 8ull * 2048 * 4;  // column sums, all 8 batches
  constexpr unsigned long long PER_B = 2 * (X_EL + QKV_EL + P_EL + VT_EL);

  size_t NB = 1;
  for (size_t nb : {(size_t)8, (size_t)4, (size_t)2})
    if (WT_B + LB_B + nb * PER_B <= ws_size) { NB = nb; break; }

  char* p = (char*)d_ws;
  bf16* Wt = (bf16*)p;   p += WT_B;
  float* lbuf = (float*)p; p += LB_B;
  bf16* Xb = (bf16*)p;   p += 2 * NB * X_EL;
  bf16* QKV = (bf16*)p;  p += 2 * NB * QKV_EL;
  bf16* P = (bf16*)p;    p += 2 * NB * P_EL;
  bf16* Vt = (bf16*)p;

  // weight transpose + zero lbuf (z==3 slice)
  wt_kernel<<<dim3(16, 16, 4), 256, 0, stream>>>(Wq, Wk, Wv, Wt, lbuf);

  for (size_t b0 = 0; b0 < 8; b0 += NB) {
    // x chunk -> bf16
    cvt_kernel<<<dim3((unsigned)(NB * 2048)), 256, 0, stream>>>(x + b0 * X_EL, Xb);
    // Q,K,V = X @ W  (z = lb*3 + weight)
    gemm_qkv<<<dim3(4, 8, (unsigned)(NB * 3)), 512, 0, stream>>>(
        Xb, Wt, QKV, 1024, 1024, 1024, 1024, 3, 3, X_EL, 1048576ull, X_EL);
    // P = exp(QK^T/32) lower-triangle tiles, causal-masked, fused column sums
    gemm_scores<<<dim3(8, 8, (unsigned)NB), 512, 0, stream>>>(
        QKV, QKV + X_EL, P, 1024, 1024, 2048, 1024, 1, 1 << 30, QKV_EL, QKV_EL, P_EL,
        lbuf + b0 * 2048);
    vhat_kernel<<<dim3(32, 16, (unsigned)NB), 256, 0, stream>>>(QKV, lbuf + b0 * 2048, Vt);
    // out = P @ Vt^T, K stops at diagonal tile
    gemm_pv<<<dim3(4, 8, (unsigned)NB), 512, 0, stream>>>(
        P, Vt, out + b0 * X_EL, 2048, 2048, 1024, 0, 1, 1 << 30, P_EL, VT_EL, X_EL);
  }
}